// Round 8
// baseline (280.694 us; speedup 1.0000x reference)
//
#include <hip/hip_runtime.h>

// Fused 5-layer MLP 203->175->150->128->80->48, tanh on 1-4, B=131072, fp32 I/O.
// Split-bf16 MFMA (v = hi+lo bf16; 3 MFMAs), 32x32x16, operand-SWAPPED:
// acc = mfma(W_frag, act_frag) -> D[feat][batch]. Legal with NO repacking:
// A/B fragment layouts are lane-symmetric (both: idx=l&31, 8 consecutive k at
// (l>>5)*8); summation order per output unchanged -> bit-identical numerics.
// R10 on the R9 shell (768 thr, 12 waves, M=64, grid 2048, 2 planes PSTR=116):
//  - K-loop: FORCED depth-2 weight / depth-1 act register pipeline. R8/R9
//    evidence: compiler flattened the even/odd pipeline (VGPR_Count 32/40) ->
//    every chunk exposed ~100-300cy of L2 latency, barrier-correlated across
//    waves -> ~70% stall (T_block 37.5us vs ~10us pipe work). Statically-
//    indexed frag arrays + sched_barrier(0) after each load cluster pin the
//    schedule (diagnostic: VGPR_Count must rise to 64-100).
//  - d_phase after swap: lane owns ONE batch row; reg-quads = 4 consecutive
//    feats -> 4x ds_write_b64 per plane (was 16 b16 ops), no col guards, no
//    PADN loops (feats >= FOUT compute exactly 0 via zero-padded W+bias).
//  - L5: guarded float4 global stores (16B-aligned: f%4==0, row stride 192B).
//  - bias: 192-entry/layer zero-padded table appended to ws (+3840 B) so
//    acc-init = 4 unguarded float4 loads indexed by feat.

typedef short short8 __attribute__((ext_vector_type(8)));
typedef float f32x16 __attribute__((ext_vector_type(16)));
typedef unsigned int uint;
typedef unsigned short ushort;

#define PSTR 116       // plane stride in dwords: mod 32 = 20 -> period-8 full-bank b128
#define NTHREADS 768
#define MROWS 64
#define BIAS_OFF (207 * 2048)   // padded bias table: 5 layers x 192 floats

__device__ __forceinline__ ushort f2bf(float f) {
    uint u = __float_as_uint(f);
    u += 0x7FFFu + ((u >> 16) & 1u);
    return (ushort)(u >> 16);
}
__device__ __forceinline__ float bf2f(ushort h) { return __uint_as_float(((uint)h) << 16); }
__device__ __forceinline__ float fast_tanh(float x) {
    float e = __expf(2.0f * x);                      // v_mul + v_mul(log2e) + v_exp
    float t = __builtin_amdgcn_rcpf(e + 1.0f);       // v_add + v_rcp
    return fmaf(-2.0f, t, 1.0f);                     // v_fma
}
// D.lo16 = bf16_rne(s0), D.hi16 = bf16_rne(s1) — bit-identical to rbf's RNE.
__device__ __forceinline__ uint cvt_pk_bf16(float s0, float s1) {
    uint r;
    asm("v_cvt_pk_bf16_f32 %0, %1, %2" : "=v"(r) : "v"(s0), "v"(s1));
    return r;
}

union U4S8 { uint4 u; short8 s; };

// ---------------- prep: split weights into ws in B-fragment order ------------
// Tile pair p = c*NT + t: 2048 B = [hi plane 1024B][lo plane 1024B], lane l
// holds W[n=l&31][k=(l>>5)*8+j] (zero-padded) — serves as A-frag after swap.
// Block 207 writes the zero-padded bias table.
__global__ void prep_weights(const float* __restrict__ W1, const float* __restrict__ W2,
                             const float* __restrict__ W3, const float* __restrict__ W4,
                             const float* __restrict__ W5,
                             const float* __restrict__ b1, const float* __restrict__ b2,
                             const float* __restrict__ b3, const float* __restrict__ b4,
                             const float* __restrict__ b5, char* __restrict__ ws)
{
    const int b = blockIdx.x, l = threadIdx.x;   // 208 blocks x 64 threads
    const int FOa[5]  = {175, 150, 128, 80, 48};
    if (b == 207) {
        float* bp = (float*)(ws + BIAS_OFF);
        const float* bs[5] = {b1, b2, b3, b4, b5};
        for (int i = l; i < 5 * 192; i += 64) {
            int L = i / 192, j = i - L * 192;
            bp[i] = (j < FOa[L]) ? bs[L][j] : 0.0f;
        }
        return;
    }
    int layer, local;
    if      (b <  78) { layer = 0; local = b; }
    else if (b < 133) { layer = 1; local = b - 78; }
    else if (b < 173) { layer = 2; local = b - 133; }
    else if (b < 197) { layer = 3; local = b - 173; }
    else              { layer = 4; local = b - 197; }
    const int NTa[5]  = {6, 5, 4, 3, 2};
    const int FINa[5] = {203, 175, 150, 128, 80};
    const float* Wp = (layer == 0) ? W1 : (layer == 1) ? W2 : (layer == 2) ? W3
                    : (layer == 3) ? W4 : W5;
    const int nt = NTa[layer], fin = FINa[layer], fout = FOa[layer];
    const int c = local / nt, t = local % nt;
    const int n  = t * 32 + (l & 31);
    const int kb = c * 16 + (l >> 5) * 8;
    uint hw[4], lw[4];
#pragma unroll
    for (int j = 0; j < 8; ++j) {
        int k = kb + j;
        float v = (n < fout && k < fin) ? Wp[(size_t)n * fin + k] : 0.0f;
        ushort hh = f2bf(v);
        ushort ll = f2bf(v - bf2f(hh));
        if (j & 1) { hw[j >> 1] |= ((uint)hh) << 16; lw[j >> 1] |= ((uint)ll) << 16; }
        else       { hw[j >> 1]  = hh;               lw[j >> 1]  = ll; }
    }
    char* dst = ws + (size_t)b * 2048 + l * 16;
    *(uint4*)dst          = make_uint4(hw[0], hw[1], hw[2], hw[3]);
    *(uint4*)(dst + 1024) = make_uint4(lw[0], lw[1], lw[2], lw[3]);
}

// ---------------- one layer: forced-pipeline K-loop, swapped MFMA ------------
// Wave w: row-group rg = w/6, N-tile t = w%6; active iff t < NT.
// D[feat][batch]: lane owns batch row rg*32+lx; reg r -> feat t*32+(r&3)+8*(r>>2)+4*lh.
template<int KC, int NT, int FOUT, bool ACT, bool LAST>
__device__ __forceinline__ void run_layer(const char* __restrict__ wsL,
    const float* __restrict__ biasP, uint* aH, uint* aL, float* outg,
    int row0, int l, int rg, int t, int lx, int lh)
{
    f32x16 acc;
    if (t < NT) {
        const float4* bp = (const float4*)(biasP + t * 32 + 4 * lh);
#pragma unroll
        for (int q = 0; q < 4; ++q) {
            float4 bv = bp[q * 2];             // feats t*32+4lh+8q .. +3 (padded)
            acc[4 * q + 0] = bv.x; acc[4 * q + 1] = bv.y;
            acc[4 * q + 2] = bv.z; acc[4 * q + 3] = bv.w;
        }

        const char* ha = (const char*)aH + (rg * 32 + lx) * (PSTR * 4) + lh * 16;
        const char* la = (const char*)aL + (rg * 32 + lx) * (PSTR * 4) + lh * 16;
        const uint4* wsb = (const uint4*)wsL + (size_t)(t * 2) * 64 + l;

        U4S8 wh[3], wl[3], ah[2], al[2];
        wh[0].u = wsb[0];                  wl[0].u = wsb[64];
        wh[1].u = wsb[(size_t)NT * 128];   wl[1].u = wsb[(size_t)NT * 128 + 64];
        ah[0].u = *(const uint4*)ha;       al[0].u = *(const uint4*)la;

#pragma unroll
        for (int c = 0; c < KC; ++c) {
            if (c + 2 < KC) {   // weight prefetch, 2 chunks ahead
                wh[(c + 2) % 3].u = wsb[(size_t)(c + 2) * NT * 128];
                wl[(c + 2) % 3].u = wsb[(size_t)(c + 2) * NT * 128 + 64];
            }
            if (c + 1 < KC) {   // act prefetch, 1 chunk ahead
                ah[(c + 1) & 1].u = *(const uint4*)(ha + (c + 1) * 32);
                al[(c + 1) & 1].u = *(const uint4*)(la + (c + 1) * 32);
            }
            __builtin_amdgcn_sched_barrier(0);   // pin: loads stay above MFMAs
            acc = __builtin_amdgcn_mfma_f32_32x32x16_bf16(wh[c % 3].s, ah[c & 1].s, acc, 0, 0, 0);
            acc = __builtin_amdgcn_mfma_f32_32x32x16_bf16(wh[c % 3].s, al[c & 1].s, acc, 0, 0, 0);
            acc = __builtin_amdgcn_mfma_f32_32x32x16_bf16(wl[c % 3].s, ah[c & 1].s, acc, 0, 0, 0);
        }
    }
    if (!LAST) __syncthreads();   // pre-D: all plane reads done before overwrite

    // D-phase: quad q = regs 4q..4q+3 = feats f..f+3, f = t*32 + 8q + 4lh.
    if (t < NT) {
        const int rowb = rg * 32 + lx;
        if (LAST) {
#pragma unroll
            for (int q = 0; q < 4; ++q) {
                const int f = t * 32 + 8 * q + 4 * lh;
                if (f + 3 < 48) {
                    float4 v = make_float4(acc[4 * q], acc[4 * q + 1],
                                           acc[4 * q + 2], acc[4 * q + 3]);
                    *(float4*)(outg + (size_t)(row0 + rowb) * 48 + f) = v;
                }
            }
        } else {
            uint* pHd = aH + rowb * PSTR;
            uint* pLd = aL + rowb * PSTR;
#pragma unroll
            for (int q = 0; q < 4; ++q) {
                float t0 = acc[4 * q], t1 = acc[4 * q + 1];
                float t2 = acc[4 * q + 2], t3 = acc[4 * q + 3];
                if (ACT) { t0 = fast_tanh(t0); t1 = fast_tanh(t1);
                           t2 = fast_tanh(t2); t3 = fast_tanh(t3); }
                uint h01 = cvt_pk_bf16(t0, t1);
                uint h23 = cvt_pk_bf16(t2, t3);
                float r0 = t0 - __uint_as_float(h01 << 16);
                float r1 = t1 - __uint_as_float(h01 & 0xFFFF0000u);
                float r2 = t2 - __uint_as_float(h23 << 16);
                float r3 = t3 - __uint_as_float(h23 & 0xFFFF0000u);
                uint l01 = cvt_pk_bf16(r0, r1);
                uint l23 = cvt_pk_bf16(r2, r3);
                const int dcol = t * 16 + 4 * q + 2 * lh;   // even -> 8B aligned
                *(uint2*)(pHd + dcol) = make_uint2(h01, h23);
                *(uint2*)(pLd + dcol) = make_uint2(l01, l23);
            }
        }
    }
    if (!LAST) __syncthreads();   // post-D: outputs visible to next layer
}

__global__ __launch_bounds__(NTHREADS, 4)
void mlp_mfma(const float* __restrict__ x,
              const char* __restrict__ ws, float* __restrict__ out)
{
    __shared__ __align__(16) uint aH[MROWS * PSTR];   // 29696 B — bf16 hi plane
    __shared__ __align__(16) uint aL[MROWS * PSTR];   // 29696 B — bf16 lo plane

    const int tid = threadIdx.x;
    const int l = tid & 63, w = tid >> 6;             // 12 waves
    const int rg = w / 6, t = w - 6 * rg;             // row-group, N-tile
    const int lx = l & 31, lh = l >> 5;
    const int row0 = blockIdx.x * MROWS;
    const float* biasT = (const float*)(ws + BIAS_OFF);

    // ---- stage + split x ONCE, pair-wise (dword cols; feats 203..207 zero) ----
    for (int e = tid; e < MROWS * 104; e += NTHREADS) {
        int row = e / 104, dcol = e - row * 104;
        int col = dcol * 2;
        const float* xp = x + (size_t)(row0 + row) * 203;
        float v0 = (col < 203) ? xp[col] : 0.0f;
        float v1 = (col + 1 < 203) ? xp[col + 1] : 0.0f;
        uint chi = cvt_pk_bf16(v0, v1);
        float h0 = __uint_as_float(chi << 16);
        float h1 = __uint_as_float(chi & 0xFFFF0000u);
        uint clo = cvt_pk_bf16(v0 - h0, v1 - h1);
        aH[row * PSTR + dcol] = chi;
        aL[row * PSTR + dcol] = clo;
    }
    __syncthreads();

    run_layer<13, 6, 175, true,  false>(ws,              biasT,       aH, aL, nullptr, row0, l, rg, t, lx, lh);
    run_layer<11, 5, 150, true,  false>(ws +  78 * 2048, biasT + 192, aH, aL, nullptr, row0, l, rg, t, lx, lh);
    run_layer<10, 4, 128, true,  false>(ws + 133 * 2048, biasT + 384, aH, aL, nullptr, row0, l, rg, t, lx, lh);
    run_layer< 8, 3,  80, true,  false>(ws + 173 * 2048, biasT + 576, aH, aL, nullptr, row0, l, rg, t, lx, lh);
    run_layer< 5, 2,  48, false, true >(ws + 197 * 2048, biasT + 768, aH, aL, out,     row0, l, rg, t, lx, lh);
}

extern "C" void kernel_launch(void* const* d_in, const int* in_sizes, int n_in,
                              void* d_out, int out_size, void* d_ws, size_t ws_size,
                              hipStream_t stream) {
    (void)in_sizes; (void)n_in; (void)ws_size; (void)out_size;
    const float* x  = (const float*)d_in[0];
    const float* W1 = (const float*)d_in[1];
    const float* b1 = (const float*)d_in[2];
    const float* W2 = (const float*)d_in[3];
    const float* b2 = (const float*)d_in[4];
    const float* W3 = (const float*)d_in[5];
    const float* b3 = (const float*)d_in[6];
    const float* W4 = (const float*)d_in[7];
    const float* b4 = (const float*)d_in[8];
    const float* W5 = (const float*)d_in[9];
    const float* b5 = (const float*)d_in[10];
    float* out = (float*)d_out;
    char* ws = (char*)d_ws;      // needs 427776 B (weights 423936 + bias pad 3840)

    hipLaunchKernelGGL(prep_weights, dim3(208), dim3(64), 0, stream,
                       W1, W2, W3, W4, W5, b1, b2, b3, b4, b5, ws);
    hipLaunchKernelGGL(mlp_mfma, dim3(131072 / MROWS), dim3(NTHREADS), 0, stream,
                       x, ws, out);
}